// Round 15
// baseline (96.340 us; speedup 1.0000x reference)
//
#include <hip/hip_runtime.h>
#include <hip/hip_bf16.h>

typedef __attribute__((ext_vector_type(8))) short bf16x8;
typedef __attribute__((ext_vector_type(4))) float f32x4;

#define NB 8
#define NT 2048
#define ND 768
#define NH 12
#define SCALE 0.125f

__device__ __forceinline__ ushort f2b(float f) {
  __hip_bfloat16 h = __float2bfloat16(f);
  return __builtin_bit_cast(ushort, h);
}
__device__ __forceinline__ float b2f(ushort u) {
  return __builtin_bit_cast(float, (unsigned int)u << 16);
}

#define GLDS(gp, lp)                                                        \
  __builtin_amdgcn_global_load_lds(                                         \
      (const __attribute__((address_space(1))) unsigned int*)(gp),          \
      (__attribute__((address_space(3))) unsigned int*)(lp), 16, 0, 0)

// ======================= fused prep (grid 3120) =======================
__global__ __launch_bounds__(256) void k0_all(
    const float* __restrict__ x, const float* __restrict__ y,
    const float* __restrict__ Wq, const float* __restrict__ Wkv,
    const float* __restrict__ Wo, ushort* __restrict__ Wvb,
    ushort* __restrict__ WT, ushort* __restrict__ xyb) {
  __shared__ float tile[64][65];
  int blk = blockIdx.x, tid = threadIdx.x;
  if (blk < 2304) {
    int i = blk * 256 + tid;
    int c = i / ND, e = i % ND;
    Wvb[i] = f2b(Wkv[(size_t)c * 1536 + 768 + e]);
  } else if (blk < 2736) {
    int idx = blk - 2304;
    int which = idx / 144, t = idx % 144;
    int kt = t / 12, nt = t % 12;
    #pragma unroll
    for (int p = 0; p < 16; ++p) {
      int i = p * 256 + tid;
      int r = i >> 6, c = i & 63;
      int gk = kt * 64 + r, gn = nt * 64 + c;
      float v;
      if (which == 0) v = Wq[(size_t)gk * ND + gn];
      else if (which == 1) v = Wkv[(size_t)gk * 1536 + gn];
      else v = Wo[(size_t)gk * ND + gn];
      tile[r][c] = v;
    }
    __syncthreads();
    #pragma unroll
    for (int p = 0; p < 2; ++p) {
      int i = p * 256 + tid;
      int n = i >> 3;
      int g8 = (i & 7) * 8;
      ushort u[8];
      #pragma unroll
      for (int e = 0; e < 8; ++e) u[e] = f2b(tile[g8 + e][n]);
      *(uint4*)&WT[(size_t)which * ND * ND + (size_t)(nt * 64 + n) * ND +
                   kt * 64 + g8] = *(const uint4*)u;
    }
  } else {
    int idx = blk - 2736;
    int which = idx / 192;
    int i = (idx % 192) * 256 + tid;
    int b = i / 6144, r8 = i % 6144;
    const float* src = (which ? y : x) + (size_t)b * NT * ND + (size_t)r8 * 8;
    float4 v0 = *(const float4*)src, v1 = *(const float4*)(src + 4);
    ushort u[8];
    u[0] = f2b(v0.x); u[1] = f2b(v0.y); u[2] = f2b(v0.z); u[3] = f2b(v0.w);
    u[4] = f2b(v1.x); u[5] = f2b(v1.y); u[6] = f2b(v1.z); u[7] = f2b(v1.w);
    *(uint4*)&xyb[((size_t)which * NB + b) * 64 * ND + (size_t)r8 * 8] =
        *(const uint4*)u;
  }
}

// ---------------- kA: fused q/k projection + scores + softmax -> attnb ----------------
__global__ __launch_bounds__(256) void kA_fused(
    const ushort* __restrict__ xyb, const ushort* __restrict__ WT,
    const float* __restrict__ bq, const float* __restrict__ bkv,
    ushort* __restrict__ attnb) {
  int h = blockIdx.x, b = blockIdx.y;
  const ushort* Ax = xyb + (size_t)b * 64 * ND;
  const ushort* Ay = xyb + (size_t)(NB + b) * 64 * ND;
  const ushort* Bq = WT + (size_t)(h * 64) * ND;
  const ushort* Bk = WT + (size_t)ND * ND + (size_t)(h * 64) * ND;

  __shared__ ushort Sx[64 * 64], Sy[64 * 64], Sq[64 * 64], Sk[64 * 64];
  __shared__ ushort qs[64][72], ks[64][72];
  int tid = threadIdx.x, w = tid >> 6, lane = tid & 63;
  int l15 = lane & 15, l4 = lane >> 4;
  int r0 = lane >> 3;
  int g = (lane & 7) ^ r0;

  f32x4 aq[4], ak[4];
  #pragma unroll
  for (int ni = 0; ni < 4; ++ni) { aq[ni] = {0.f,0.f,0.f,0.f}; ak[ni] = {0.f,0.f,0.f,0.f}; }

  for (int t = 0; t < 12; ++t) {
    __syncthreads();
    #pragma unroll
    for (int cc = 0; cc < 2; ++cc) {
      int c = w + cc * 4;
      int row = c * 8 + r0;
      size_t off = (size_t)row * ND + t * 64 + g * 8;
      GLDS(&Ax[off], &Sx[c * 512]);
      GLDS(&Ay[off], &Sy[c * 512]);
      GLDS(&Bq[off], &Sq[c * 512]);
      GLDS(&Bk[off], &Sk[c * 512]);
    }
    __syncthreads();
    #pragma unroll
    for (int kk = 0; kk < 2; ++kk) {
      int arow = w * 16 + l15;
      int aslot = ((kk * 4 + l4) ^ (arow & 7)) * 8;
      bf16x8 afx = *(const bf16x8*)&Sx[arow * 64 + aslot];
      bf16x8 afy = *(const bf16x8*)&Sy[arow * 64 + aslot];
      #pragma unroll
      for (int ni = 0; ni < 4; ++ni) {
        int brow = ni * 16 + l15;
        int bslot = ((kk * 4 + l4) ^ (brow & 7)) * 8;
        bf16x8 bfq = *(const bf16x8*)&Sq[brow * 64 + bslot];
        bf16x8 bfk = *(const bf16x8*)&Sk[brow * 64 + bslot];
        aq[ni] = __builtin_amdgcn_mfma_f32_16x16x32_bf16(afx, bfq, aq[ni], 0, 0, 0);
        ak[ni] = __builtin_amdgcn_mfma_f32_16x16x32_bf16(afy, bfk, ak[ni], 0, 0, 0);
      }
    }
  }
  __syncthreads();
  #pragma unroll
  for (int ni = 0; ni < 4; ++ni) {
    int col = ni * 16 + l15;
    float bvq = bq[h * 64 + col];
    float bvk = bkv[h * 64 + col];
    #pragma unroll
    for (int j = 0; j < 4; ++j) {
      int row = w * 16 + l4 * 4 + j;
      qs[row][col] = f2b(aq[ni][j] + bvq);
      ks[row][col] = f2b(ak[ni][j] + bvk);
    }
  }
  __syncthreads();
  f32x4 as_[4];
  #pragma unroll
  for (int ni = 0; ni < 4; ++ni) as_[ni] = {0.f, 0.f, 0.f, 0.f};
  #pragma unroll
  for (int kk = 0; kk < 2; ++kk) {
    int arow = w * 16 + l15;
    bf16x8 af = *(const bf16x8*)&qs[arow][kk * 32 + l4 * 8];
    #pragma unroll
    for (int ni = 0; ni < 4; ++ni) {
      bf16x8 bf = *(const bf16x8*)&ks[ni * 16 + l15][kk * 32 + l4 * 8];
      as_[ni] = __builtin_amdgcn_mfma_f32_16x16x32_bf16(af, bf, as_[ni], 0, 0, 0);
    }
  }
  ushort* dst = attnb + (size_t)(b * NH + h) * 64 * 64;
  #pragma unroll
  for (int j = 0; j < 4; ++j) {
    float v[4];
    #pragma unroll
    for (int ni = 0; ni < 4; ++ni) v[ni] = as_[ni][j] * SCALE;
    float m = fmaxf(fmaxf(v[0], v[1]), fmaxf(v[2], v[3]));
    #pragma unroll
    for (int d = 1; d < 16; d <<= 1) m = fmaxf(m, __shfl_xor(m, d));
    float e[4], s = 0.f;
    #pragma unroll
    for (int ni = 0; ni < 4; ++ni) { e[ni] = expf(v[ni] - m); s += e[ni]; }
    #pragma unroll
    for (int d = 1; d < 16; d <<= 1) s += __shfl_xor(s, d);
    float rs = 1.0f / s;
    int row = w * 16 + l4 * 4 + j;
    #pragma unroll
    for (int ni = 0; ni < 4; ++ni)
      dst[row * 64 + ni * 16 + l15] = f2b(e[ni] * rs);
  }
}

// ---------------- k2_mfma ----------------
__global__ __launch_bounds__(256) void k2_mfma(const ushort* __restrict__ attnb,
                                               const ushort* __restrict__ WT,
                                               ushort* __restrict__ PT) {
  int jt = blockIdx.x, h = blockIdx.y, b = blockIdx.z;
  const ushort* Ag = WT + (size_t)2 * ND * ND + (size_t)jt * 128 * ND + h * 64;
  const ushort* Bg = attnb + (size_t)(b * NH + h) * 64 * 64;

  __shared__ ushort As[128 * 64];
  __shared__ ushort Bs[64 * 64];
  int tid = threadIdx.x, w = tid >> 6, lane = tid & 63;
  int wr = (w >> 1) * 64, wc = (w & 1) * 32;
  int l15 = lane & 15, l4 = lane >> 4;
  int r0 = lane >> 3;
  int g = (lane & 7) ^ r0;

  #pragma unroll
  for (int cc = 0; cc < 4; ++cc) {
    int c = w + cc * 4;
    int row = c * 8 + r0;
    GLDS(&Ag[(size_t)row * ND + g * 8], &As[c * 512]);
  }
  #pragma unroll
  for (int cc = 0; cc < 2; ++cc) {
    int c = w + cc * 4;
    int row = c * 8 + r0;
    GLDS(&Bg[(size_t)row * 64 + g * 8], &Bs[c * 512]);
  }
  __syncthreads();

  f32x4 acc[4][2];
  #pragma unroll
  for (int mi = 0; mi < 4; ++mi)
    #pragma unroll
    for (int ni = 0; ni < 2; ++ni) acc[mi][ni] = {0.f, 0.f, 0.f, 0.f};

  #pragma unroll
  for (int kk = 0; kk < 2; ++kk) {
    bf16x8 bfr[2];
    #pragma unroll
    for (int ni = 0; ni < 2; ++ni) {
      int rb = wc + ni * 16 + l15;
      int slot = (kk * 4 + l4) ^ (rb & 7);
      bfr[ni] = *(const bf16x8*)&Bs[rb * 64 + slot * 8];
    }
    #pragma unroll
    for (int mi = 0; mi < 4; ++mi) {
      int ra = wr + mi * 16 + l15;
      int slot = (kk * 4 + l4) ^ (ra & 7);
      bf16x8 af = *(const bf16x8*)&As[ra * 64 + slot * 8];
      #pragma unroll
      for (int ni = 0; ni < 2; ++ni)
        acc[mi][ni] = __builtin_amdgcn_mfma_f32_16x16x32_bf16(af, bfr[ni],
                                                              acc[mi][ni], 0, 0, 0);
    }
  }
  #pragma unroll
  for (int mi = 0; mi < 4; ++mi)
    #pragma unroll
    for (int ni = 0; ni < 2; ++ni) {
      int d = wc + ni * 16 + l15;
      #pragma unroll
      for (int j = 0; j < 4; ++j) {
        int jr = jt * 128 + wr + mi * 16 + l4 * 4 + j;
        PT[(size_t)b * ND * ND + (size_t)jr * ND + h * 64 + d] = f2b(acc[mi][ni][j]);
      }
    }
}

// ---------------- k2b_f ----------------
__global__ __launch_bounds__(256) void k2b_f(const ushort* __restrict__ attnb,
                                             const float* __restrict__ Wo,
                                             const float* __restrict__ bkv,
                                             const float* __restrict__ bo,
                                             float* __restrict__ cvec) {
  int jt = blockIdx.x, b = blockIdx.y;
  int tid = threadIdx.x;
  __shared__ float bl[768];
  __shared__ f32x4 red[256];
  for (int i = tid; i < ND; i += 256) {
    int h = i >> 6, s = i & 63;
    const ushort* at = attnb + (size_t)(b * NH + h) * 64 * 64;
    float acc = 0.f;
    #pragma unroll 8
    for (int d = 0; d < 64; ++d) acc += bkv[768 + h * 64 + d] * b2f(at[d * 64 + s]);
    bl[i] = acc;
  }
  __syncthreads();
  int jq = tid & 31;
  int es = tid >> 5;
  int j0 = jt * 128 + jq * 4;
  f32x4 acc = {0.f, 0.f, 0.f, 0.f};
  #pragma unroll 8
  for (int e = es * 96; e < es * 96 + 96; ++e) {
    float4 w = *(const float4*)&Wo[(size_t)e * ND + j0];
    float bv = bl[e];
    acc[0] += bv * w.x; acc[1] += bv * w.y;
    acc[2] += bv * w.z; acc[3] += bv * w.w;
  }
  red[tid] = acc;
  __syncthreads();
  if (tid < 32) {
    f32x4 s = red[tid];
    #pragma unroll
    for (int k = 1; k < 8; ++k) {
      f32x4 r = red[tid + 32 * k];
      s[0] += r[0]; s[1] += r[1]; s[2] += r[2]; s[3] += r[3];
    }
    #pragma unroll
    for (int c = 0; c < 4; ++c)
      cvec[b * ND + j0 + c] = s[c] + bo[j0 + c];
  }
}

// ---------------- k3: MT = PT@WvbT + I (round-10 proven dbuf loop) ----------------
__global__ __launch_bounds__(256, 3) void k3_gemm(const ushort* __restrict__ PT,
                                                  const ushort* __restrict__ Wvb,
                                                  ushort* __restrict__ MT) {
  int flat = blockIdx.x;
  int b = flat & 7;
  int t0 = flat >> 3;
  int rowt = t0 / 6, colt = t0 % 6;
  const ushort* Ag = PT + (size_t)b * ND * ND + (size_t)rowt * 128 * ND;
  const ushort* Bg = Wvb + (size_t)colt * 128 * ND;
  ushort* Cout = MT + (size_t)b * ND * ND + (size_t)rowt * 128 * ND + colt * 128;

  __shared__ ushort As[2][128 * 32];
  __shared__ ushort Bs[2][128 * 32];
  int tid = threadIdx.x, w = tid >> 6, lane = tid & 63;
  int wr = (w >> 1) * 64, wc = (w & 1) * 64;
  int l15 = lane & 15, l4 = lane >> 4;
  int r0 = lane >> 2, q = lane & 3;

  f32x4 acc[4][4];
  #pragma unroll
  for (int mi = 0; mi < 4; ++mi)
    #pragma unroll
    for (int ni = 0; ni < 4; ++ni) acc[mi][ni] = {0.f, 0.f, 0.f, 0.f};

  auto STAGE = [&](int bufi, int kk) {
    #pragma unroll
    for (int cc = 0; cc < 2; ++cc) {
      int c = w + cc * 4;
      int row = c * 16 + r0;
      int sq = (q ^ ((row >> 1) & 3)) * 8;
      GLDS(&Ag[(size_t)row * ND + kk + sq], &As[bufi][c * 512]);
      GLDS(&Bg[(size_t)row * ND + kk + sq], &Bs[bufi][c * 512]);
    }
  };

  STAGE(0, 0);
  __syncthreads();
  int cur = 0;
  for (int t2 = 0; t2 < 24; ++t2) {
    if (t2 + 1 < 24) STAGE(cur ^ 1, (t2 + 1) * 32);
    bf16x8 af[4], bfr[4];
    #pragma unroll
    for (int mi = 0; mi < 4; ++mi) {
      int r = wr + mi * 16 + l15;
      af[mi] = *(const bf16x8*)&As[cur][r * 32 + (l4 ^ ((r >> 1) & 3)) * 8];
    }
    #pragma unroll
    for (int ni = 0; ni < 4; ++ni) {
      int r = wc + ni * 16 + l15;
      bfr[ni] = *(const bf16x8*)&Bs[cur][r * 32 + (l4 ^ ((r >> 1) & 3)) * 8];
    }
    #pragma unroll
    for (int mi = 0; mi < 4; ++mi)
      #pragma unroll
      for (int ni = 0; ni < 4; ++ni)
        acc[mi][ni] = __builtin_amdgcn_mfma_f32_16x16x32_bf16(af[mi], bfr[ni],
                                                              acc[mi][ni], 0, 0, 0);
    __syncthreads();
    cur ^= 1;
  }
  bool diagt = (rowt == colt);
  #pragma unroll
  for (int mi = 0; mi < 4; ++mi)
    #pragma unroll
    for (int ni = 0; ni < 4; ++ni)
      #pragma unroll
      for (int j = 0; j < 4; ++j) {
        int r = wr + mi * 16 + l4 * 4 + j;
        int c = wc + ni * 16 + l15;
        float v = acc[mi][ni][j] + ((diagt && r == c) ? 1.0f : 0.0f);
        Cout[(size_t)r * ND + c] = f2b(v);
      }
}

// ---------------- k4n: out[b] = y[b]@(M_b+I) + cvec[b], 64x256 tiles ----------------
// A-traffic halved: each y 64-row panel read 3x (vs 6x at BN=128).
// 768 blocks (8b x 32 rowt x 3 colt, XCD-pinned, colt fastest -> L2 panel
// sharing). 256 thr / 4 waves; wave w = all 64 rows x cols [w*64, w*64+64),
// acc[4][4]; As broadcast-shared. LDS 40KB -> 4 blocks/CU.
// A: reg-staged f32->bf16 rotation swizzle; B: GLDS pre-swizzled source.
__global__ __launch_bounds__(256, 4) void k4n_gemm(const float* __restrict__ y,
                                                   const ushort* __restrict__ MT,
                                                   const float* __restrict__ cvec,
                                                   float* __restrict__ out) {
  int flat = blockIdx.x;                    // 0..767
  int work = (flat & 7) * 96 + (flat >> 3); // XCD x <- batch x (bijective)
  int b = work / 96;
  int rem = work % 96;
  int rowt = rem / 3;   // 32 row tiles of 64
  int colt = rem % 3;   // 3 col tiles of 256 (fastest -> L2 panel reuse)
  const float* Ag = y + (size_t)b * NT * ND + (size_t)rowt * 64 * ND;
  const ushort* Bg = MT + (size_t)b * ND * ND + (size_t)colt * 256 * ND;
  float* Out = out + (size_t)b * NT * ND;

  __shared__ ushort As[2][64 * 32];    // 4 KiB each
  __shared__ ushort Bs[2][256 * 32];   // 16 KiB each
  int tid = threadIdx.x, w = tid >> 6, lane = tid & 63;
  int wc = w * 64;                     // wave's column slice
  int l15 = lane & 15, l4 = lane >> 4;
  int br = lane >> 2, bq = lane & 3;   // B staging (16 rows/chunk, 4 q)
  int ar = tid >> 2;                   // A staging row (4 threads/row, 64 rows)
  int aq4 = tid & 3;                   // A quarter (8 f32)

  f32x4 acc[4][4];
  #pragma unroll
  for (int mi = 0; mi < 4; ++mi)
    #pragma unroll
    for (int ni = 0; ni < 4; ++ni) acc[mi][ni] = {0.f, 0.f, 0.f, 0.f};

  float4 ra[2];
  auto AISSUE = [&](int kt) {
    ra[0] = *(const float4*)&Ag[(size_t)ar * ND + kt * 32 + aq4 * 8];
    ra[1] = *(const float4*)&Ag[(size_t)ar * ND + kt * 32 + aq4 * 8 + 4];
  };
  auto AWRITE = [&](int bufi) {
    ushort u[8];
    #pragma unroll
    for (int e = 0; e < 4; ++e) { u[e] = f2b(ra[0][e]); u[4 + e] = f2b(ra[1][e]); }
    int g0 = (aq4 + (ar >> 1)) & 3;    // rotation granule swizzle (proven class)
    *(uint4*)&As[bufi][ar * 32 + g0 * 8] = *(const uint4*)u;
  };
  auto BSTAGE = [&](int bufi, int kt) {
    #pragma unroll
    for (int cc = 0; cc < 4; ++cc) {
      int c = w + cc * 4;              // chunk 0..15 (16 rows x 32 bf16 = 1KB)
      int row = c * 16 + br;
      int sq = (bq ^ ((row >> 1) & 3)) * 8;
      GLDS(&Bg[(size_t)row * ND + kt * 32 + sq], &Bs[bufi][c * 512]);
    }
  };

  AISSUE(0);
  BSTAGE(0, 0);
  AWRITE(0);
  __syncthreads();
  int cur = 0;
  for (int t = 0; t < 24; ++t) {
    bool more = (t + 1 < 24);
    if (more) { AISSUE(t + 1); BSTAGE(cur ^ 1, t + 1); }
    bf16x8 af[4], bfr[4];
    #pragma unroll
    for (int mi = 0; mi < 4; ++mi) {
      int r = mi * 16 + l15;
      int gg = (l4 + (r >> 1)) & 3;    // match AWRITE rotation
      af[mi] = *(const bf16x8*)&As[cur][r * 32 + gg * 8];
    }
    #pragma unroll
    for (int ni = 0; ni < 4; ++ni) {
      int r = wc + ni * 16 + l15;
      bfr[ni] = *(const bf16x8*)&Bs[cur][r * 32 + (l4 ^ ((r >> 1) & 3)) * 8];
    }
    #pragma unroll
    for (int mi = 0; mi < 4; ++mi)
      #pragma unroll
      for (int ni = 0; ni < 4; ++ni)
        acc[mi][ni] = __builtin_amdgcn_mfma_f32_16x16x32_bf16(af[mi], bfr[ni],
                                                              acc[mi][ni], 0, 0, 0);
    if (more) AWRITE(cur ^ 1);
    __syncthreads();
    cur ^= 1;
  }
  #pragma unroll
  for (int mi = 0; mi < 4; ++mi)
    #pragma unroll
    for (int ni = 0; ni < 4; ++ni) {
      int gc = colt * 256 + wc + ni * 16 + l15;
      float cv = cvec[b * ND + gc];
      #pragma unroll
      for (int j = 0; j < 4; ++j) {
        int gr = rowt * 64 + mi * 16 + l4 * 4 + j;
        Out[(size_t)gr * ND + gc] = acc[mi][ni][j] + cv;
      }
    }
}

// ======================= fallback chain (small ws) =======================
__global__ __launch_bounds__(256) void k0_prep(const float* __restrict__ Wkv,
                                               ushort* __restrict__ Wvb) {
  int i = blockIdx.x * 256 + threadIdx.x;
  int c = i / ND, e = i % ND;
  Wvb[i] = f2b(Wkv[(size_t)c * 1536 + 768 + e]);
}
__global__ __launch_bounds__(512) void k1a_qk(
    const float* __restrict__ x, const float* __restrict__ y,
    const float* __restrict__ Wq, const float* __restrict__ bq,
    const float* __restrict__ Wkv, const float* __restrict__ bkv,
    float* __restrict__ qk) {
  int h = blockIdx.x, b = blockIdx.y, which = blockIdx.z;
  const float* src = which ? y : x;
  __shared__ float sA[64][68];
  __shared__ float sB[64][68];
  int tid = threadIdx.x;
  int tx = tid & 15, ty = tid >> 4;
  float acc[2][4] = {{0.f,0.f,0.f,0.f},{0.f,0.f,0.f,0.f}};
  for (int kt = 0; kt < 12; ++kt) {
    __syncthreads();
    #pragma unroll
    for (int p = 0; p < 8; ++p) {
      int i = p * 512 + tid;
      int r = i >> 6, c = i & 63;
      sA[r][c] = src[(size_t)b * NT * ND + r * ND + kt * 64 + c];
      sB[r][c] = which ? Wkv[(size_t)(kt * 64 + r) * 1536 + h * 64 + c]
                       : Wq[(size_t)(kt * 64 + r) * ND + h * 64 + c];
    }
    __syncthreads();
    #pragma unroll 8
    for (int kk = 0; kk < 64; ++kk) {
      float4 bv = *(const float4*)&sB[kk][tx * 4];
      float a0 = sA[ty * 2 + 0][kk];
      float a1 = sA[ty * 2 + 1][kk];
      acc[0][0] += a0 * bv.x; acc[0][1] += a0 * bv.y;
      acc[0][2] += a0 * bv.z; acc[0][3] += a0 * bv.w;
      acc[1][0] += a1 * bv.x; acc[1][1] += a1 * bv.y;
      acc[1][2] += a1 * bv.z; acc[1][3] += a1 * bv.w;
    }
  }
  const float* bias = which ? bkv : bq;
  float* dst = qk + ((size_t)which * NB + b) * 64 * ND;
  #pragma unroll
  for (int i2 = 0; i2 < 2; ++i2)
    #pragma unroll
    for (int j = 0; j < 4; ++j)
      dst[(ty * 2 + i2) * ND + h * 64 + tx * 4 + j] =
          acc[i2][j] + bias[h * 64 + tx * 4 + j];
}
__global__ __launch_bounds__(256) void k1b_attn(const float* __restrict__ qk,
                                                float* __restrict__ attn) {
  int h = blockIdx.x, b = blockIdx.y;
  __shared__ float qs2[64][68];
  __shared__ float ks2[64][68];
  __shared__ float sc[64][68];
  __shared__ float rm[64], rs[64];
  int tid = threadIdx.x;
  #pragma unroll
  for (int p = 0; p < 16; ++p) {
    int i = p * 256 + tid;
    int r = i >> 6, c = i & 63;
    qs2[r][c] = qk[(size_t)b * 64 * ND + r * ND + h * 64 + c];
    ks2[r][c] = qk[(size_t)(NB + b) * 64 * ND + r * ND + h * 64 + c];
  }
  __syncthreads();
  int tx = tid & 15, ty = tid >> 4;
  float a[4][4] = {};
  #pragma unroll 8
  for (int kk = 0; kk < 64; ++kk) {
    float qv[4], kv[4];
    #pragma unroll
    for (int i = 0; i < 4; ++i) qv[i] = qs2[ty * 4 + i][kk];
    #pragma unroll
    for (int j = 0; j < 4; ++j) kv[j] = ks2[tx * 4 + j][kk];
    #pragma unroll
    for (int i = 0; i < 4; ++i)
      #pragma unroll
      for (int j = 0; j < 4; ++j) a[i][j] += qv[i] * kv[j];
  }
  #pragma unroll
  for (int i = 0; i < 4; ++i)
    #pragma unroll
    for (int j = 0; j < 4; ++j)
      sc[ty * 4 + i][tx * 4 + j] = a[i][j] * SCALE;
  __syncthreads();
  if (tid < 64) {
    float m = -1e30f;
    for (int z = 0; z < 64; ++z) m = fmaxf(m, sc[tid][z]);
    float s = 0.f;
    for (int z = 0; z < 64; ++z) s += expf(sc[tid][z] - m);
    rm[tid] = m;
    rs[tid] = 1.0f / s;
  }
  __syncthreads();
  #pragma unroll
  for (int p = 0; p < 16; ++p) {
    int i = p * 256 + tid;
    int r = i >> 6, c = i & 63;
    attn[((size_t)(b * NH + h) * 64 + r) * 64 + c] =
        expf(sc[r][c] - rm[r]) * rs[r];
  }
}
__global__ __launch_bounds__(256) void k2_pt(const float* __restrict__ attn,
                                             const float* __restrict__ Wo,
                                             ushort* __restrict__ PT) {
  int jt = blockIdx.x, h = blockIdx.y, b = blockIdx.z;
  __shared__ float at[64][64];
  int tid = threadIdx.x;
  #pragma unroll
  for (int p = 0; p < 16; ++p) {
    int i = p * 256 + tid;
    int d = i >> 6, s = i & 63;
    at[d][s] = attn[((size_t)(b * NH + h) * 64 + d) * 64 + s];
  }
  __syncthreads();
  int tx = tid & 31, ty = tid >> 5;
  int j0 = jt * 128 + tx * 4;
  float acc[8][4] = {};
  for (int s = 0; s < 64; ++s) {
    float4 w = *(const float4*)&Wo[(size_t)(h * 64 + s) * ND + j0];
    #pragma unroll
    for (int dd = 0; dd < 8; ++dd) {
      float av = at[ty * 8 + dd][s];
      acc[dd][0] += av * w.x; acc[dd][1] += av * w.y;
      acc[dd][2] += av * w.z; acc[dd][3] += av * w.w;
    }
  }
  #pragma unroll
  for (int jj = 0; jj < 4; ++jj) {
    ushort tmp[8];
    #pragma unroll
    for (int dd = 0; dd < 8; ++dd) tmp[dd] = f2b(acc[dd][jj]);
    *(uint4*)&PT[(size_t)b * ND * ND + (size_t)(j0 + jj) * ND + h * 64 + ty * 8] =
        *(const uint4*)tmp;
  }
}
__global__ __launch_bounds__(256) void k2b1_bva(const float* __restrict__ attn,
                                                const float* __restrict__ bkv,
                                                float* __restrict__ bvA) {
  int b = blockIdx.x;
  int tid = threadIdx.x;
  for (int i = tid; i < ND; i += 256) {
    int h = i >> 6, s = i & 63;
    const float* at = attn + (size_t)(b * NH + h) * 64 * 64;
    float acc = 0.f;
    #pragma unroll 8
    for (int d = 0; d < 64; ++d) acc += bkv[768 + h * 64 + d] * at[d * 64 + s];
    bvA[b * ND + i] = acc;
  }
}
__global__ __launch_bounds__(256) void k2b2_cvec(const float* __restrict__ bvA,
                                                 const float* __restrict__ Wo,
                                                 const float* __restrict__ bo,
                                                 float* __restrict__ cvec) {
  int jt = blockIdx.x, b = blockIdx.y;
  int tid = threadIdx.x;
  __shared__ float bl[768];
  __shared__ f32x4 red[256];
  for (int i = tid; i < ND; i += 256) bl[i] = bvA[b * ND + i];
  __syncthreads();
  int jq = tid & 31, es = tid >> 5;
  int j0 = jt * 128 + jq * 4;
  f32x4 acc = {0.f, 0.f, 0.f, 0.f};
  #pragma unroll 8
  for (int e = es * 96; e < es * 96 + 96; ++e) {
    float4 w = *(const float4*)&Wo[(size_t)e * ND + j0];
    float bv = bl[e];
    acc[0] += bv * w.x; acc[1] += bv * w.y;
    acc[2] += bv * w.z; acc[3] += bv * w.w;
  }
  red[tid] = acc;
  __syncthreads();
  if (tid < 32) {
    f32x4 s = red[tid];
    #pragma unroll
    for (int k = 1; k < 8; ++k) {
      f32x4 r = red[tid + 32 * k];
      s[0] += r[0]; s[1] += r[1]; s[2] += r[2]; s[3] += r[3];
    }
    #pragma unroll
    for (int c = 0; c < 4; ++c)
      cvec[b * ND + j0 + c] = s[c] + bo[j0 + c];
  }
}

extern "C" void kernel_launch(void* const* d_in, const int* in_sizes, int n_in,
                              void* d_out, int out_size, void* d_ws, size_t ws_size,
                              hipStream_t stream) {
  const float* x = (const float*)d_in[0];
  const float* y = (const float*)d_in[1];
  const float* Wq = (const float*)d_in[2];
  const float* bq = (const float*)d_in[3];
  const float* Wkv = (const float*)d_in[4];
  const float* bkv = (const float*)d_in[5];
  const float* Wo = (const float*)d_in[6];
  const float* bo = (const float*)d_in[7];
  float* out = (float*)d_out;
  char* ws = (char*)d_ws;

  // MAIN layout (25,976,832 bytes) — measured ws_size >= this.
  ushort* attnb = (ushort*)(ws + 0);
  float*  cvecM = (float*)(ws + 786432);
  ushort* WvbM  = (ushort*)(ws + 811008);
  ushort* PTM   = (ushort*)(ws + 1990656);
  ushort* MTM   = (ushort*)(ws + 11427840);
  ushort* WT    = (ushort*)(ws + 20865024);
  ushort* xyb   = (ushort*)(ws + 24403968);
  bool MAIN = ws_size >= 25976832ull;

  if (MAIN) {
    k0_all<<<dim3(3120), 256, 0, stream>>>(x, y, Wq, Wkv, Wo, WvbM, WT, xyb);
    kA_fused<<<dim3(NH, NB), 256, 0, stream>>>(xyb, WT, bq, bkv, attnb);
    k2_mfma<<<dim3(6, NH, NB), 256, 0, stream>>>(attnb, WT, PTM);
    k2b_f<<<dim3(6, NB), 256, 0, stream>>>(attnb, Wo, bkv, bo, cvecM);
    k3_gemm<<<dim3(288), 256, 0, stream>>>(PTM, WvbM, MTM);
    k4n_gemm<<<dim3(768), 256, 0, stream>>>(y, MTM, cvecM, out);
    return;
  }

  // Fallback layout (24,797,184 bytes)
  float* qk    = (float*)(ws + 0);
  float* attn  = (float*)(ws + 3145728);
  float* cvec  = (float*)(ws + 4718592);
  ushort* Wvb  = (ushort*)(ws + 4743168);
  ushort* PT   = (ushort*)(ws + 5922816);
  ushort* MT   = (ushort*)(ws + 15360000);
  float* bvA   = (float*)(ws + 0);

  k0_prep<<<dim3(2304), 256, 0, stream>>>(Wkv, Wvb);
  k1a_qk<<<dim3(NH, NB, 2), 512, 0, stream>>>(x, y, Wq, bq, Wkv, bkv, qk);
  k1b_attn<<<dim3(NH, NB), 256, 0, stream>>>(qk, attn);
  k2_pt<<<dim3(6, NH, NB), 256, 0, stream>>>(attn, Wo, PT);
  k2b1_bva<<<dim3(NB), 256, 0, stream>>>(attn, bkv, bvA);
  k2b2_cvec<<<dim3(6, NB), 256, 0, stream>>>(bvA, Wo, bo, cvec);
  k3_gemm<<<dim3(288), 256, 0, stream>>>(PT, Wvb, MT);
  k4n_gemm<<<dim3(768), 256, 0, stream>>>(y, MT, cvec, out);
}

// Round 16
// 92.348 us; speedup vs baseline: 1.0432x; 1.0432x over previous
//
#include <hip/hip_runtime.h>
#include <hip/hip_bf16.h>

typedef __attribute__((ext_vector_type(8))) short bf16x8;
typedef __attribute__((ext_vector_type(4))) float f32x4;

#define NB 8
#define NT 2048
#define ND 768
#define NH 12
#define SCALE 0.125f

__device__ __forceinline__ ushort f2b(float f) {
  __hip_bfloat16 h = __float2bfloat16(f);
  return __builtin_bit_cast(ushort, h);
}
__device__ __forceinline__ float b2f(ushort u) {
  return __builtin_bit_cast(float, (unsigned int)u << 16);
}

#define GLDS(gp, lp)                                                        \
  __builtin_amdgcn_global_load_lds(                                         \
      (const __attribute__((address_space(1))) unsigned int*)(gp),          \
      (__attribute__((address_space(3))) unsigned int*)(lp), 16, 0, 0)

// ======================= fused prep (grid 3120) =======================
__global__ __launch_bounds__(256) void k0_all(
    const float* __restrict__ x, const float* __restrict__ y,
    const float* __restrict__ Wq, const float* __restrict__ Wkv,
    const float* __restrict__ Wo, ushort* __restrict__ Wvb,
    ushort* __restrict__ WT, ushort* __restrict__ xyb) {
  __shared__ float tile[64][65];
  int blk = blockIdx.x, tid = threadIdx.x;
  if (blk < 2304) {
    int i = blk * 256 + tid;
    int c = i / ND, e = i % ND;
    Wvb[i] = f2b(Wkv[(size_t)c * 1536 + 768 + e]);
  } else if (blk < 2736) {
    int idx = blk - 2304;
    int which = idx / 144, t = idx % 144;
    int kt = t / 12, nt = t % 12;
    #pragma unroll
    for (int p = 0; p < 16; ++p) {
      int i = p * 256 + tid;
      int r = i >> 6, c = i & 63;
      int gk = kt * 64 + r, gn = nt * 64 + c;
      float v;
      if (which == 0) v = Wq[(size_t)gk * ND + gn];
      else if (which == 1) v = Wkv[(size_t)gk * 1536 + gn];
      else v = Wo[(size_t)gk * ND + gn];
      tile[r][c] = v;
    }
    __syncthreads();
    #pragma unroll
    for (int p = 0; p < 2; ++p) {
      int i = p * 256 + tid;
      int n = i >> 3;
      int g8 = (i & 7) * 8;
      ushort u[8];
      #pragma unroll
      for (int e = 0; e < 8; ++e) u[e] = f2b(tile[g8 + e][n]);
      *(uint4*)&WT[(size_t)which * ND * ND + (size_t)(nt * 64 + n) * ND +
                   kt * 64 + g8] = *(const uint4*)u;
    }
  } else {
    int idx = blk - 2736;
    int which = idx / 192;
    int i = (idx % 192) * 256 + tid;
    int b = i / 6144, r8 = i % 6144;
    const float* src = (which ? y : x) + (size_t)b * NT * ND + (size_t)r8 * 8;
    float4 v0 = *(const float4*)src, v1 = *(const float4*)(src + 4);
    ushort u[8];
    u[0] = f2b(v0.x); u[1] = f2b(v0.y); u[2] = f2b(v0.z); u[3] = f2b(v0.w);
    u[4] = f2b(v1.x); u[5] = f2b(v1.y); u[6] = f2b(v1.z); u[7] = f2b(v1.w);
    *(uint4*)&xyb[((size_t)which * NB + b) * 64 * ND + (size_t)r8 * 8] =
        *(const uint4*)u;
  }
}

// ---------------- kA: fused q/k projection + scores + softmax -> attnb ----------------
__global__ __launch_bounds__(256) void kA_fused(
    const ushort* __restrict__ xyb, const ushort* __restrict__ WT,
    const float* __restrict__ bq, const float* __restrict__ bkv,
    ushort* __restrict__ attnb) {
  int h = blockIdx.x, b = blockIdx.y;
  const ushort* Ax = xyb + (size_t)b * 64 * ND;
  const ushort* Ay = xyb + (size_t)(NB + b) * 64 * ND;
  const ushort* Bq = WT + (size_t)(h * 64) * ND;
  const ushort* Bk = WT + (size_t)ND * ND + (size_t)(h * 64) * ND;

  __shared__ ushort Sx[64 * 64], Sy[64 * 64], Sq[64 * 64], Sk[64 * 64];
  __shared__ ushort qs[64][72], ks[64][72];
  int tid = threadIdx.x, w = tid >> 6, lane = tid & 63;
  int l15 = lane & 15, l4 = lane >> 4;
  int r0 = lane >> 3;
  int g = (lane & 7) ^ r0;

  f32x4 aq[4], ak[4];
  #pragma unroll
  for (int ni = 0; ni < 4; ++ni) { aq[ni] = {0.f,0.f,0.f,0.f}; ak[ni] = {0.f,0.f,0.f,0.f}; }

  for (int t = 0; t < 12; ++t) {
    __syncthreads();
    #pragma unroll
    for (int cc = 0; cc < 2; ++cc) {
      int c = w + cc * 4;
      int row = c * 8 + r0;
      size_t off = (size_t)row * ND + t * 64 + g * 8;
      GLDS(&Ax[off], &Sx[c * 512]);
      GLDS(&Ay[off], &Sy[c * 512]);
      GLDS(&Bq[off], &Sq[c * 512]);
      GLDS(&Bk[off], &Sk[c * 512]);
    }
    __syncthreads();
    #pragma unroll
    for (int kk = 0; kk < 2; ++kk) {
      int arow = w * 16 + l15;
      int aslot = ((kk * 4 + l4) ^ (arow & 7)) * 8;
      bf16x8 afx = *(const bf16x8*)&Sx[arow * 64 + aslot];
      bf16x8 afy = *(const bf16x8*)&Sy[arow * 64 + aslot];
      #pragma unroll
      for (int ni = 0; ni < 4; ++ni) {
        int brow = ni * 16 + l15;
        int bslot = ((kk * 4 + l4) ^ (brow & 7)) * 8;
        bf16x8 bfq = *(const bf16x8*)&Sq[brow * 64 + bslot];
        bf16x8 bfk = *(const bf16x8*)&Sk[brow * 64 + bslot];
        aq[ni] = __builtin_amdgcn_mfma_f32_16x16x32_bf16(afx, bfq, aq[ni], 0, 0, 0);
        ak[ni] = __builtin_amdgcn_mfma_f32_16x16x32_bf16(afy, bfk, ak[ni], 0, 0, 0);
      }
    }
  }
  __syncthreads();
  #pragma unroll
  for (int ni = 0; ni < 4; ++ni) {
    int col = ni * 16 + l15;
    float bvq = bq[h * 64 + col];
    float bvk = bkv[h * 64 + col];
    #pragma unroll
    for (int j = 0; j < 4; ++j) {
      int row = w * 16 + l4 * 4 + j;
      qs[row][col] = f2b(aq[ni][j] + bvq);
      ks[row][col] = f2b(ak[ni][j] + bvk);
    }
  }
  __syncthreads();
  f32x4 as_[4];
  #pragma unroll
  for (int ni = 0; ni < 4; ++ni) as_[ni] = {0.f, 0.f, 0.f, 0.f};
  #pragma unroll
  for (int kk = 0; kk < 2; ++kk) {
    int arow = w * 16 + l15;
    bf16x8 af = *(const bf16x8*)&qs[arow][kk * 32 + l4 * 8];
    #pragma unroll
    for (int ni = 0; ni < 4; ++ni) {
      bf16x8 bf = *(const bf16x8*)&ks[ni * 16 + l15][kk * 32 + l4 * 8];
      as_[ni] = __builtin_amdgcn_mfma_f32_16x16x32_bf16(af, bf, as_[ni], 0, 0, 0);
    }
  }
  ushort* dst = attnb + (size_t)(b * NH + h) * 64 * 64;
  #pragma unroll
  for (int j = 0; j < 4; ++j) {
    float v[4];
    #pragma unroll
    for (int ni = 0; ni < 4; ++ni) v[ni] = as_[ni][j] * SCALE;
    float m = fmaxf(fmaxf(v[0], v[1]), fmaxf(v[2], v[3]));
    #pragma unroll
    for (int d = 1; d < 16; d <<= 1) m = fmaxf(m, __shfl_xor(m, d));
    float e[4], s = 0.f;
    #pragma unroll
    for (int ni = 0; ni < 4; ++ni) { e[ni] = expf(v[ni] - m); s += e[ni]; }
    #pragma unroll
    for (int d = 1; d < 16; d <<= 1) s += __shfl_xor(s, d);
    float rs = 1.0f / s;
    int row = w * 16 + l4 * 4 + j;
    #pragma unroll
    for (int ni = 0; ni < 4; ++ni)
      dst[row * 64 + ni * 16 + l15] = f2b(e[ni] * rs);
  }
}

// ---------------- k2m: PT (MFMA) + cvec fused; grid (6, NH+1, NB) ----------------
__global__ __launch_bounds__(256) void k2m(const ushort* __restrict__ attnb,
                                           const ushort* __restrict__ WT,
                                           const float* __restrict__ Wo,
                                           const float* __restrict__ bkv,
                                           const float* __restrict__ bo,
                                           ushort* __restrict__ PT,
                                           float* __restrict__ cvec) {
  int jt = blockIdx.x, hy = blockIdx.y, b = blockIdx.z;
  int tid = threadIdx.x;
  if (hy == NH) {  // cvec slice (old k2b_f)
    __shared__ float bl[768];
    __shared__ f32x4 red[256];
    for (int i = tid; i < ND; i += 256) {
      int h = i >> 6, s = i & 63;
      const ushort* at = attnb + (size_t)(b * NH + h) * 64 * 64;
      float acc = 0.f;
      #pragma unroll 8
      for (int d = 0; d < 64; ++d) acc += bkv[768 + h * 64 + d] * b2f(at[d * 64 + s]);
      bl[i] = acc;
    }
    __syncthreads();
    int jq = tid & 31;
    int es = tid >> 5;
    int j0 = jt * 128 + jq * 4;
    f32x4 acc = {0.f, 0.f, 0.f, 0.f};
    #pragma unroll 8
    for (int e = es * 96; e < es * 96 + 96; ++e) {
      float4 w = *(const float4*)&Wo[(size_t)e * ND + j0];
      float bv = bl[e];
      acc[0] += bv * w.x; acc[1] += bv * w.y;
      acc[2] += bv * w.z; acc[3] += bv * w.w;
    }
    red[tid] = acc;
    __syncthreads();
    if (tid < 32) {
      f32x4 s = red[tid];
      #pragma unroll
      for (int k = 1; k < 8; ++k) {
        f32x4 r = red[tid + 32 * k];
        s[0] += r[0]; s[1] += r[1]; s[2] += r[2]; s[3] += r[3];
      }
      #pragma unroll
      for (int c = 0; c < 4; ++c)
        cvec[b * ND + j0 + c] = s[c] + bo[j0 + c];
    }
    return;
  }
  int h = hy;
  const ushort* Ag = WT + (size_t)2 * ND * ND + (size_t)jt * 128 * ND + h * 64;
  const ushort* Bg = attnb + (size_t)(b * NH + h) * 64 * 64;

  __shared__ ushort As[128 * 64];
  __shared__ ushort Bs[64 * 64];
  int w = tid >> 6, lane = tid & 63;
  int wr = (w >> 1) * 64, wc = (w & 1) * 32;
  int l15 = lane & 15, l4 = lane >> 4;
  int r0 = lane >> 3;
  int g = (lane & 7) ^ r0;

  #pragma unroll
  for (int cc = 0; cc < 4; ++cc) {
    int c = w + cc * 4;
    int row = c * 8 + r0;
    GLDS(&Ag[(size_t)row * ND + g * 8], &As[c * 512]);
  }
  #pragma unroll
  for (int cc = 0; cc < 2; ++cc) {
    int c = w + cc * 4;
    int row = c * 8 + r0;
    GLDS(&Bg[(size_t)row * 64 + g * 8], &Bs[c * 512]);
  }
  __syncthreads();

  f32x4 acc[4][2];
  #pragma unroll
  for (int mi = 0; mi < 4; ++mi)
    #pragma unroll
    for (int ni = 0; ni < 2; ++ni) acc[mi][ni] = {0.f, 0.f, 0.f, 0.f};

  #pragma unroll
  for (int kk = 0; kk < 2; ++kk) {
    bf16x8 bfr[2];
    #pragma unroll
    for (int ni = 0; ni < 2; ++ni) {
      int rb = wc + ni * 16 + l15;
      int slot = (kk * 4 + l4) ^ (rb & 7);
      bfr[ni] = *(const bf16x8*)&Bs[rb * 64 + slot * 8];
    }
    #pragma unroll
    for (int mi = 0; mi < 4; ++mi) {
      int ra = wr + mi * 16 + l15;
      int slot = (kk * 4 + l4) ^ (ra & 7);
      bf16x8 af = *(const bf16x8*)&As[ra * 64 + slot * 8];
      #pragma unroll
      for (int ni = 0; ni < 2; ++ni)
        acc[mi][ni] = __builtin_amdgcn_mfma_f32_16x16x32_bf16(af, bfr[ni],
                                                              acc[mi][ni], 0, 0, 0);
    }
  }
  #pragma unroll
  for (int mi = 0; mi < 4; ++mi)
    #pragma unroll
    for (int ni = 0; ni < 2; ++ni) {
      int d = wc + ni * 16 + l15;
      #pragma unroll
      for (int j = 0; j < 4; ++j) {
        int jr = jt * 128 + wr + mi * 16 + l4 * 4 + j;
        PT[(size_t)b * ND * ND + (size_t)jr * ND + h * 64 + d] = f2b(acc[mi][ni][j]);
      }
    }
}

// ---------------- k3: MT = PT@WvbT + I — 64x128 tiles, 576 blocks ----------------
__global__ __launch_bounds__(256, 4) void k3_gemm(const ushort* __restrict__ PT,
                                                  const ushort* __restrict__ Wvb,
                                                  ushort* __restrict__ MT) {
  int flat = blockIdx.x;                 // 0..575
  int b = flat & 7;                      // XCD-pinned
  int t0 = flat >> 3;                    // 0..71
  int rowt = t0 / 6;                     // 12 row tiles of 64 (j)
  int colt = t0 % 6;                     // 6 col tiles of 128 (c)
  const ushort* Ag = PT + (size_t)b * ND * ND + (size_t)rowt * 64 * ND;
  const ushort* Bg = Wvb + (size_t)colt * 128 * ND;
  ushort* Cout = MT + (size_t)b * ND * ND + (size_t)rowt * 64 * ND + colt * 128;

  __shared__ ushort As[2][64 * 32];      // 4 KiB each
  __shared__ ushort Bs[2][128 * 32];     // 8 KiB each
  int tid = threadIdx.x, w = tid >> 6, lane = tid & 63;
  int wr = (w >> 1) * 32, wc = (w & 1) * 64;
  int l15 = lane & 15, l4 = lane >> 4;
  int r0 = lane >> 2, q = lane & 3;

  f32x4 acc[2][4];
  #pragma unroll
  for (int mi = 0; mi < 2; ++mi)
    #pragma unroll
    for (int ni = 0; ni < 4; ++ni) acc[mi][ni] = {0.f, 0.f, 0.f, 0.f};

  auto STAGE = [&](int bufi, int kk) {
    {  // A: 4 chunks (16 rows each); wave w stages chunk w
      int row = w * 16 + r0;
      int sq = (q ^ ((row >> 1) & 3)) * 8;
      GLDS(&Ag[(size_t)row * ND + kk + sq], &As[bufi][w * 512]);
    }
    #pragma unroll
    for (int cc = 0; cc < 2; ++cc) {  // B: 8 chunks
      int c = w + cc * 4;
      int row = c * 16 + r0;
      int sq = (q ^ ((row >> 1) & 3)) * 8;
      GLDS(&Bg[(size_t)row * ND + kk + sq], &Bs[bufi][c * 512]);
    }
  };

  STAGE(0, 0);
  __syncthreads();
  int cur = 0;
  for (int t2 = 0; t2 < 24; ++t2) {
    if (t2 + 1 < 24) STAGE(cur ^ 1, (t2 + 1) * 32);
    bf16x8 af[2], bfr[4];
    #pragma unroll
    for (int mi = 0; mi < 2; ++mi) {
      int r = wr + mi * 16 + l15;
      af[mi] = *(const bf16x8*)&As[cur][r * 32 + (l4 ^ ((r >> 1) & 3)) * 8];
    }
    #pragma unroll
    for (int ni = 0; ni < 4; ++ni) {
      int r = wc + ni * 16 + l15;
      bfr[ni] = *(const bf16x8*)&Bs[cur][r * 32 + (l4 ^ ((r >> 1) & 3)) * 8];
    }
    #pragma unroll
    for (int mi = 0; mi < 2; ++mi)
      #pragma unroll
      for (int ni = 0; ni < 4; ++ni)
        acc[mi][ni] = __builtin_amdgcn_mfma_f32_16x16x32_bf16(af[mi], bfr[ni],
                                                              acc[mi][ni], 0, 0, 0);
    __syncthreads();
    cur ^= 1;
  }
  #pragma unroll
  for (int mi = 0; mi < 2; ++mi)
    #pragma unroll
    for (int ni = 0; ni < 4; ++ni)
      #pragma unroll
      for (int j = 0; j < 4; ++j) {
        int r = wr + mi * 16 + l4 * 4 + j;       // local row 0..63
        int c = wc + ni * 16 + l15;              // local col 0..127
        int gj = rowt * 64 + r, gc2 = colt * 128 + c;
        float v = acc[mi][ni][j] + ((gj == gc2) ? 1.0f : 0.0f);
        Cout[(size_t)r * ND + c] = f2b(v);
      }
}

// ---------------- k4w: out[b] = y[b]@(M_b+I) + cvec[b], 512 thr / 8 waves ----------------
// Round-14 best-measured k4 (93.0µs total). Proven dbuf + single barrier.
__global__ __launch_bounds__(512, 6) void k4w_gemm(const float* __restrict__ y,
                                                   const ushort* __restrict__ MT,
                                                   const float* __restrict__ cvec,
                                                   float* __restrict__ out) {
  int flat = blockIdx.x;                    // 0..767
  int work = (flat & 7) * 96 + (flat >> 3); // XCD x <- batch x (bijective)
  int b = work / 96;
  int rem = work % 96;
  int rowt = rem / 6;
  int colt = rem % 6;
  const float* Ag = y + (size_t)b * NT * ND + (size_t)rowt * 128 * ND;
  const ushort* Bg = MT + (size_t)b * ND * ND + (size_t)colt * 128 * ND;
  float* Out = out + (size_t)b * NT * ND;

  __shared__ ushort As[2][128 * 32];
  __shared__ ushort Bs[2][128 * 32];
  int tid = threadIdx.x, w = tid >> 6, lane = tid & 63;
  int wr = (w >> 2) * 64;
  int wc = (w & 3) * 32;
  int l15 = lane & 15, l4 = lane >> 4;
  int br = lane >> 2, bq = lane & 3;
  int ar = tid >> 2;
  int aq4 = tid & 3;

  f32x4 acc[4][2];
  #pragma unroll
  for (int mi = 0; mi < 4; ++mi)
    #pragma unroll
    for (int ni = 0; ni < 2; ++ni) acc[mi][ni] = {0.f, 0.f, 0.f, 0.f};

  float4 ra[2];
  auto AISSUE = [&](int kt) {
    ra[0] = *(const float4*)&Ag[(size_t)ar * ND + kt * 32 + aq4 * 8];
    ra[1] = *(const float4*)&Ag[(size_t)ar * ND + kt * 32 + aq4 * 8 + 4];
  };
  auto AWRITE = [&](int bufi) {
    ushort u[8];
    #pragma unroll
    for (int e = 0; e < 4; ++e) { u[e] = f2b(ra[0][e]); u[4 + e] = f2b(ra[1][e]); }
    int g0 = (aq4 + (ar >> 1)) & 3;
    *(uint4*)&As[bufi][ar * 32 + g0 * 8] = *(const uint4*)u;
  };
  auto BSTAGE = [&](int bufi, int kt) {
    int row = w * 16 + br;
    int sq = (bq ^ ((row >> 1) & 3)) * 8;
    GLDS(&Bg[(size_t)row * ND + kt * 32 + sq], &Bs[bufi][w * 512]);
  };

  AISSUE(0);
  BSTAGE(0, 0);
  AWRITE(0);
  __syncthreads();
  int cur = 0;
  for (int t = 0; t < 24; ++t) {
    bool more = (t + 1 < 24);
    if (more) { AISSUE(t + 1); BSTAGE(cur ^ 1, t + 1); }
    bf16x8 af[4], bfr[2];
    #pragma unroll
    for (int mi = 0; mi < 4; ++mi) {
      int r = wr + mi * 16 + l15;
      int gg = (l4 + (r >> 1)) & 3;
      af[mi] = *(const bf16x8*)&As[cur][r * 32 + gg * 8];
    }
    #pragma unroll
    for (int ni = 0; ni < 2; ++ni) {
      int r = wc + ni * 16 + l15;
      bfr[ni] = *(const bf16x8*)&Bs[cur][r * 32 + (l4 ^ ((r >> 1) & 3)) * 8];
    }
    #pragma unroll
    for (int mi = 0; mi < 4; ++mi)
      #pragma unroll
      for (int ni = 0; ni < 2; ++ni)
        acc[mi][ni] = __builtin_amdgcn_mfma_f32_16x16x32_bf16(af[mi], bfr[ni],
                                                              acc[mi][ni], 0, 0, 0);
    if (more) AWRITE(cur ^ 1);
    __syncthreads();
    cur ^= 1;
  }
  #pragma unroll
  for (int mi = 0; mi < 4; ++mi)
    #pragma unroll
    for (int ni = 0; ni < 2; ++ni) {
      int gc = colt * 128 + wc + ni * 16 + l15;
      float cv = cvec[b * ND + gc];
      #pragma unroll
      for (int j = 0; j < 4; ++j) {
        int gr = rowt * 128 + wr + mi * 16 + l4 * 4 + j;
        Out[(size_t)gr * ND + gc] = acc[mi][ni][j] + cv;
      }
    }
}

// ======================= fallback chain (small ws) =======================
__global__ __launch_bounds__(256) void k0_prep(const float* __restrict__ Wkv,
                                               ushort* __restrict__ Wvb) {
  int i = blockIdx.x * 256 + threadIdx.x;
  int c = i / ND, e = i % ND;
  Wvb[i] = f2b(Wkv[(size_t)c * 1536 + 768 + e]);
}
__global__ __launch_bounds__(512) void k1a_qk(
    const float* __restrict__ x, const float* __restrict__ y,
    const float* __restrict__ Wq, const float* __restrict__ bq,
    const float* __restrict__ Wkv, const float* __restrict__ bkv,
    float* __restrict__ qk) {
  int h = blockIdx.x, b = blockIdx.y, which = blockIdx.z;
  const float* src = which ? y : x;
  __shared__ float sA[64][68];
  __shared__ float sB[64][68];
  int tid = threadIdx.x;
  int tx = tid & 15, ty = tid >> 4;
  float acc[2][4] = {{0.f,0.f,0.f,0.f},{0.f,0.f,0.f,0.f}};
  for (int kt = 0; kt < 12; ++kt) {
    __syncthreads();
    #pragma unroll
    for (int p = 0; p < 8; ++p) {
      int i = p * 512 + tid;
      int r = i >> 6, c = i & 63;
      sA[r][c] = src[(size_t)b * NT * ND + r * ND + kt * 64 + c];
      sB[r][c] = which ? Wkv[(size_t)(kt * 64 + r) * 1536 + h * 64 + c]
                       : Wq[(size_t)(kt * 64 + r) * ND + h * 64 + c];
    }
    __syncthreads();
    #pragma unroll 8
    for (int kk = 0; kk < 64; ++kk) {
      float4 bv = *(const float4*)&sB[kk][tx * 4];
      float a0 = sA[ty * 2 + 0][kk];
      float a1 = sA[ty * 2 + 1][kk];
      acc[0][0] += a0 * bv.x; acc[0][1] += a0 * bv.y;
      acc[0][2] += a0 * bv.z; acc[0][3] += a0 * bv.w;
      acc[1][0] += a1 * bv.x; acc[1][1] += a1 * bv.y;
      acc[1][2] += a1 * bv.z; acc[1][3] += a1 * bv.w;
    }
  }
  const float* bias = which ? bkv : bq;
  float* dst = qk + ((size_t)which * NB + b) * 64 * ND;
  #pragma unroll
  for (int i2 = 0; i2 < 2; ++i2)
    #pragma unroll
    for (int j = 0; j < 4; ++j)
      dst[(ty * 2 + i2) * ND + h * 64 + tx * 4 + j] =
          acc[i2][j] + bias[h * 64 + tx * 4 + j];
}
__global__ __launch_bounds__(256) void k1b_attn(const float* __restrict__ qk,
                                                float* __restrict__ attn) {
  int h = blockIdx.x, b = blockIdx.y;
  __shared__ float qs2[64][68];
  __shared__ float ks2[64][68];
  __shared__ float sc[64][68];
  __shared__ float rm[64], rs[64];
  int tid = threadIdx.x;
  #pragma unroll
  for (int p = 0; p < 16; ++p) {
    int i = p * 256 + tid;
    int r = i >> 6, c = i & 63;
    qs2[r][c] = qk[(size_t)b * 64 * ND + r * ND + h * 64 + c];
    ks2[r][c] = qk[(size_t)(NB + b) * 64 * ND + r * ND + h * 64 + c];
  }
  __syncthreads();
  int tx = tid & 15, ty = tid >> 4;
  float a[4][4] = {};
  #pragma unroll 8
  for (int kk = 0; kk < 64; ++kk) {
    float qv[4], kv[4];
    #pragma unroll
    for (int i = 0; i < 4; ++i) qv[i] = qs2[ty * 4 + i][kk];
    #pragma unroll
    for (int j = 0; j < 4; ++j) kv[j] = ks2[tx * 4 + j][kk];
    #pragma unroll
    for (int i = 0; i < 4; ++i)
      #pragma unroll
      for (int j = 0; j < 4; ++j) a[i][j] += qv[i] * kv[j];
  }
  #pragma unroll
  for (int i = 0; i < 4; ++i)
    #pragma unroll
    for (int j = 0; j < 4; ++j)
      sc[ty * 4 + i][tx * 4 + j] = a[i][j] * SCALE;
  __syncthreads();
  if (tid < 64) {
    float m = -1e30f;
    for (int z = 0; z < 64; ++z) m = fmaxf(m, sc[tid][z]);
    float s = 0.f;
    for (int z = 0; z < 64; ++z) s += expf(sc[tid][z] - m);
    rm[tid] = m;
    rs[tid] = 1.0f / s;
  }
  __syncthreads();
  #pragma unroll
  for (int p = 0; p < 16; ++p) {
    int i = p * 256 + tid;
    int r = i >> 6, c = i & 63;
    attn[((size_t)(b * NH + h) * 64 + r) * 64 + c] =
        expf(sc[r][c] - rm[r]) * rs[r];
  }
}
__global__ __launch_bounds__(256) void k2_pt(const float* __restrict__ attn,
                                             const float* __restrict__ Wo,
                                             ushort* __restrict__ PT) {
  int jt = blockIdx.x, h = blockIdx.y, b = blockIdx.z;
  __shared__ float at[64][64];
  int tid = threadIdx.x;
  #pragma unroll
  for (int p = 0; p < 16; ++p) {
    int i = p * 256 + tid;
    int d = i >> 6, s = i & 63;
    at[d][s] = attn[((size_t)(b * NH + h) * 64 + d) * 64 + s];
  }
  __syncthreads();
  int tx = tid & 31, ty = tid >> 5;
  int j0 = jt * 128 + tx * 4;
  float acc[8][4] = {};
  for (int s = 0; s < 64; ++s) {
    float4 w = *(const float4*)&Wo[(size_t)(h * 64 + s) * ND + j0];
    #pragma unroll
    for (int dd = 0; dd < 8; ++dd) {
      float av = at[ty * 8 + dd][s];
      acc[dd][0] += av * w.x; acc[dd][1] += av * w.y;
      acc[dd][2] += av * w.z; acc[dd][3] += av * w.w;
    }
  }
  #pragma unroll
  for (int jj = 0; jj < 4; ++jj) {
    ushort tmp[8];
    #pragma unroll
    for (int dd = 0; dd < 8; ++dd) tmp[dd] = f2b(acc[dd][jj]);
    *(uint4*)&PT[(size_t)b * ND * ND + (size_t)(j0 + jj) * ND + h * 64 + ty * 8] =
        *(const uint4*)tmp;
  }
}
__global__ __launch_bounds__(256) void k2b1_bva(const float* __restrict__ attn,
                                                const float* __restrict__ bkv,
                                                float* __restrict__ bvA) {
  int b = blockIdx.x;
  int tid = threadIdx.x;
  for (int i = tid; i < ND; i += 256) {
    int h = i >> 6, s = i & 63;
    const float* at = attn + (size_t)(b * NH + h) * 64 * 64;
    float acc = 0.f;
    #pragma unroll 8
    for (int d = 0; d < 64; ++d) acc += bkv[768 + h * 64 + d] * at[d * 64 + s];
    bvA[b * ND + i] = acc;
  }
}
__global__ __launch_bounds__(256) void k2b2_cvec(const float* __restrict__ bvA,
                                                 const float* __restrict__ Wo,
                                                 const float* __restrict__ bo,
                                                 float* __restrict__ cvec) {
  int jt = blockIdx.x, b = blockIdx.y;
  int tid = threadIdx.x;
  __shared__ float bl[768];
  __shared__ f32x4 red[256];
  for (int i = tid; i < ND; i += 256) bl[i] = bvA[b * ND + i];
  __syncthreads();
  int jq = tid & 31, es = tid >> 5;
  int j0 = jt * 128 + jq * 4;
  f32x4 acc = {0.f, 0.f, 0.f, 0.f};
  #pragma unroll 8
  for (int e = es * 96; e < es * 96 + 96; ++e) {
    float4 w = *(const float4*)&Wo[(size_t)e * ND + j0];
    float bv = bl[e];
    acc[0] += bv * w.x; acc[1] += bv * w.y;
    acc[2] += bv * w.z; acc[3] += bv * w.w;
  }
  red[tid] = acc;
  __syncthreads();
  if (tid < 32) {
    f32x4 s = red[tid];
    #pragma unroll
    for (int k = 1; k < 8; ++k) {
      f32x4 r = red[tid + 32 * k];
      s[0] += r[0]; s[1] += r[1]; s[2] += r[2]; s[3] += r[3];
    }
    #pragma unroll
    for (int c = 0; c < 4; ++c)
      cvec[b * ND + j0 + c] = s[c] + bo[j0 + c];
  }
}

extern "C" void kernel_launch(void* const* d_in, const int* in_sizes, int n_in,
                              void* d_out, int out_size, void* d_ws, size_t ws_size,
                              hipStream_t stream) {
  const float* x = (const float*)d_in[0];
  const float* y = (const float*)d_in[1];
  const float* Wq = (const float*)d_in[2];
  const float* bq = (const float*)d_in[3];
  const float* Wkv = (const float*)d_in[4];
  const float* bkv = (const float*)d_in[5];
  const float* Wo = (const float*)d_in[6];
  const float* bo = (const float*)d_in[7];
  float* out = (float*)d_out;
  char* ws = (char*)d_ws;

  // MAIN layout (25,976,832 bytes) — measured ws_size >= this.
  ushort* attnb = (ushort*)(ws + 0);
  float*  cvecM = (float*)(ws + 786432);
  ushort* WvbM  = (ushort*)(ws + 811008);
  ushort* PTM   = (ushort*)(ws + 1990656);
  ushort* MTM   = (ushort*)(ws + 11427840);
  ushort* WT    = (ushort*)(ws + 20865024);
  ushort* xyb   = (ushort*)(ws + 24403968);
  bool MAIN = ws_size >= 25976832ull;

  if (MAIN) {
    k0_all<<<dim3(3120), 256, 0, stream>>>(x, y, Wq, Wkv, Wo, WvbM, WT, xyb);
    kA_fused<<<dim3(NH, NB), 256, 0, stream>>>(xyb, WT, bq, bkv, attnb);
    k2m<<<dim3(6, NH + 1, NB), 256, 0, stream>>>(attnb, WT, Wo, bkv, bo, PTM, cvecM);
    k3_gemm<<<dim3(576), 256, 0, stream>>>(PTM, WvbM, MTM);
    k4w_gemm<<<dim3(768), 512, 0, stream>>>(y, MTM, cvecM, out);
    return;
  }

  // Fallback layout (24,797,184 bytes)
  float* qk    = (float*)(ws + 0);
  float* attn  = (float*)(ws + 3145728);
  float* cvec  = (float*)(ws + 4718592);
  ushort* Wvb  = (ushort*)(ws + 4743168);
  ushort* PT   = (ushort*)(ws + 5922816);
  ushort* MT   = (ushort*)(ws + 15360000);
  float* bvA   = (float*)(ws + 0);

  k0_prep<<<dim3(2304), 256, 0, stream>>>(Wkv, Wvb);
  k1a_qk<<<dim3(NH, NB, 2), 512, 0, stream>>>(x, y, Wq, bq, Wkv, bkv, qk);
  k1b_attn<<<dim3(NH, NB), 256, 0, stream>>>(qk, attn);
  k2_pt<<<dim3(6, NH, NB), 256, 0, stream>>>(attn, Wo, PT);
  k2b1_bva<<<dim3(NB), 256, 0, stream>>>(attn, bkv, bvA);
  k2b2_cvec<<<dim3(6, NB), 256, 0, stream>>>(bvA, Wo, bo, cvec);
  k3_gemm<<<dim3(576), 256, 0, stream>>>(PT, Wvb, MT);
  k4w_gemm<<<dim3(768), 512, 0, stream>>>(y, MT, cvec, out);
}